// Round 7
// baseline (401.435 us; speedup 1.0000x reference)
//
#include <hip/hip_runtime.h>

// Problem dims (fixed by the reference)
constexpr int cB = 32, cT = 15, cV = 100, cD = 768, cN = 160, cAP = 7;
constexpr int cD4 = cD / 4;         // 192 float4 per row
constexpr int cTV = cT * cV;        // 1500 candidate entries per batch
constexpr int cNQ = 4;              // partial quarters per visited step
constexpr int cXB = cNQ * cT;       // 60 helper blocks per batch
constexpr float cLN_EPS = 1e-12f;

// ---------------------------------------------------------------------------
// Single compute kernel: grid (cN + 60, cB) x 192.
//   nb <  cN : output-row block (pos GEMV + LN + step emb; candidate gather).
//              Visited rows write BASE only, then join the ticket.
//   nb >= cN : helper block -> sum quarter q of step t into ws partial.
// 5th arriver on ticket[b*cT+t] adds the 4 partials * (1/len) onto the row.
__global__ __launch_bounds__(192) void k_all(
    const float4* __restrict__ emb,      // [B*T*V, D/4]
    const float*  __restrict__ pos_fts,  // [B,N,7]
    const float4* __restrict__ step_tab, // [100, D/4]
    const float4* __restrict__ pos_w,    // [7, D/4]
    const float4* __restrict__ pos_b,    // [D/4]
    const float4* __restrict__ ln_g,     // [D/4]
    const float4* __restrict__ ln_b,     // [D/4]
    const int*    __restrict__ vp_lens,  // [B,T]
    const int*    __restrict__ vpids,    // [B,T]
    const int*    __restrict__ cand_ids, // [B,T,V]
    const int*    __restrict__ step_ids, // [B,N]
    int*          __restrict__ ticket,   // [B*T], zeroed each launch
    float4*       __restrict__ wsp,      // [B*T*4, D/4] partial sums
    float4*       __restrict__ out)      // [B*N, D/4]
{
    const int nb  = blockIdx.x;          // 0..cN+59
    const int b   = blockIdx.y;          // 0..31
    const int tid = threadIdx.x;         // 0..191, owns float4 slot tid

    __shared__ int   slen[cT], svp[cT];
    __shared__ float sf[cAP];
    __shared__ float red[8];
    __shared__ int   scount, sOld;
    __shared__ int   slist[cTV];         // contributor entries (t*V+v), 6 KB

    if (tid < cT) slen[tid] = vp_lens[b * cT + tid];
    if (tid >= 32 && tid < 32 + cT) svp[tid - 32] = vpids[b * cT + (tid - 32)];

    // ---------------- helper blocks: one quarter of one step ----------------
    if (nb >= cN) {
        __syncthreads();
        const int j  = nb - cN;          // 0..59
        const int t  = j >> 2;
        const int q  = j & 3;
        const int bt = b * cT + t;
        const int len = slen[t];
        const int lo = (len * q) >> 2;
        const int hi = (len * (q + 1)) >> 2;
        float ax = 0.f, ay = 0.f, az = 0.f, aw = 0.f;
        const float4* base = emb + (size_t)bt * cV * cD4 + tid;
        int i = lo;
        for (; i + 8 <= hi; i += 8) {
            const float4 a0 = base[(size_t)(i + 0) * cD4];
            const float4 a1 = base[(size_t)(i + 1) * cD4];
            const float4 a2 = base[(size_t)(i + 2) * cD4];
            const float4 a3 = base[(size_t)(i + 3) * cD4];
            const float4 a4 = base[(size_t)(i + 4) * cD4];
            const float4 a5 = base[(size_t)(i + 5) * cD4];
            const float4 a6 = base[(size_t)(i + 6) * cD4];
            const float4 a7 = base[(size_t)(i + 7) * cD4];
            ax += ((a0.x + a1.x) + (a2.x + a3.x)) + ((a4.x + a5.x) + (a6.x + a7.x));
            ay += ((a0.y + a1.y) + (a2.y + a3.y)) + ((a4.y + a5.y) + (a6.y + a7.y));
            az += ((a0.z + a1.z) + (a2.z + a3.z)) + ((a4.z + a5.z) + (a6.z + a7.z));
            aw += ((a0.w + a1.w) + (a2.w + a3.w)) + ((a4.w + a5.w) + (a6.w + a7.w));
        }
        for (; i + 4 <= hi; i += 4) {
            const float4 a0 = base[(size_t)(i + 0) * cD4];
            const float4 a1 = base[(size_t)(i + 1) * cD4];
            const float4 a2 = base[(size_t)(i + 2) * cD4];
            const float4 a3 = base[(size_t)(i + 3) * cD4];
            ax += (a0.x + a1.x) + (a2.x + a3.x);
            ay += (a0.y + a1.y) + (a2.y + a3.y);
            az += (a0.z + a1.z) + (a2.z + a3.z);
            aw += (a0.w + a1.w) + (a2.w + a3.w);
        }
        for (; i < hi; ++i) {
            const float4 a0 = base[(size_t)i * cD4];
            ax += a0.x; ay += a0.y; az += a0.z; aw += a0.w;
        }
        wsp[(size_t)(bt * cNQ + q) * cD4 + tid] = make_float4(ax, ay, az, aw);
        __threadfence();
        __syncthreads();
        if (tid == 0) sOld = atomicAdd(&ticket[bt], 1);
        __syncthreads();
        if (sOld == cNQ) {               // 5th arriver -> combine
            __threadfence();
            const int node = svp[t];
            const float w  = 1.0f / (float)len;
            const size_t pb = (size_t)(bt * cNQ) * cD4 + tid;
            const float4 p0 = wsp[pb];
            const float4 p1 = wsp[pb + cD4];
            const float4 p2 = wsp[pb + 2 * cD4];
            const float4 p3 = wsp[pb + 3 * cD4];
            const size_t orow = (size_t)(b * cN + node) * cD4 + tid;
            float4 o = out[orow];
            o.x += ((p0.x + p1.x) + (p2.x + p3.x)) * w;
            o.y += ((p0.y + p1.y) + (p2.y + p3.y)) * w;
            o.z += ((p0.z + p1.z) + (p2.z + p3.z)) * w;
            o.w += ((p0.w + p1.w) + (p2.w + p3.w)) * w;
            out[orow] = o;
        }
        return;
    }

    // ---------------- output-row blocks ----------------
    const int n   = nb;
    const int row = b * cN + n;
    if (tid >= 64 && tid < 64 + cAP) sf[tid - 64] = pos_fts[row * cAP + (tid - 64)];
    if (tid == 0) scount = 0;
    __syncthreads();

    // which step visited this node (largest t wins, matches scatter override)
    int tvis = -1;
#pragma unroll
    for (int k = cT - 1; k >= 0; --k) if (tvis < 0 && svp[k] == n) tvis = k;

    // candidate rows: scan this batch's 1500 cand ids (int4) + LDS compact
    const bool isCand = (n > 0) && (tvis < 0);
    if (isCand) {
        const int4* cb4 = (const int4*)(cand_ids + (size_t)b * cTV);
        for (int u = tid; u < cTV / 4; u += 192) {
            const int4 c4 = cb4[u];
            const int e0 = u * 4;
            const int cc[4] = {c4.x, c4.y, c4.z, c4.w};
#pragma unroll
            for (int k = 0; k < 4; ++k) {
                const int e = e0 + k;
                const int t = e / cV;
                const int v = e - t * cV;
                if (cc[k] == n && v < slen[t]) slist[atomicAdd(&scount, 1)] = e;
            }
        }
    }

    // pos GEMV: 4 outputs per thread (overlaps the scan's loads)
    float4 x = pos_b[tid];
#pragma unroll
    for (int k = 0; k < cAP; ++k) {
        const float4 w = pos_w[k * cD4 + tid];
        const float f = sf[k];
        x.x = fmaf(f, w.x, x.x); x.y = fmaf(f, w.y, x.y);
        x.z = fmaf(f, w.z, x.z); x.w = fmaf(f, w.w, x.w);
    }
    float s  = x.x + x.y + x.z + x.w;
    float ss = x.x * x.x + x.y * x.y + x.z * x.z + x.w * x.w;
    for (int off = 32; off; off >>= 1) {
        s  += __shfl_down(s,  off, 64);
        ss += __shfl_down(ss, off, 64);
    }
    if ((tid & 63) == 0) { red[(tid >> 6) * 2] = s; red[(tid >> 6) * 2 + 1] = ss; }
    __syncthreads();                      // also orders slist writes
    if (tid == 0) {
        const float S  = red[0] + red[2] + red[4];
        const float SS = red[1] + red[3] + red[5];
        const float mu  = S / (float)cD;
        const float var = SS / (float)cD - mu * mu;
        red[6] = mu;
        red[7] = rsqrtf(fmaxf(var, 0.f) + cLN_EPS);
    }
    __syncthreads();
    const float mu = red[6], rs = red[7];

    // candidate gather (visited rows contribute base only; helpers do the rest)
    float ax = 0.f, ay = 0.f, az = 0.f, aw = 0.f;
    float wgt = 0.f;
    if (isCand) {
        const int m = scount;
        if (m > 0) {
            const float4* base = emb + (size_t)b * cTV * cD4 + tid;
            int j = 0;
            for (; j + 8 <= m; j += 8) {
                const float4 a0 = base[(size_t)slist[j + 0] * cD4];
                const float4 a1 = base[(size_t)slist[j + 1] * cD4];
                const float4 a2 = base[(size_t)slist[j + 2] * cD4];
                const float4 a3 = base[(size_t)slist[j + 3] * cD4];
                const float4 a4 = base[(size_t)slist[j + 4] * cD4];
                const float4 a5 = base[(size_t)slist[j + 5] * cD4];
                const float4 a6 = base[(size_t)slist[j + 6] * cD4];
                const float4 a7 = base[(size_t)slist[j + 7] * cD4];
                ax += ((a0.x + a1.x) + (a2.x + a3.x)) + ((a4.x + a5.x) + (a6.x + a7.x));
                ay += ((a0.y + a1.y) + (a2.y + a3.y)) + ((a4.y + a5.y) + (a6.y + a7.y));
                az += ((a0.z + a1.z) + (a2.z + a3.z)) + ((a4.z + a5.z) + (a6.z + a7.z));
                aw += ((a0.w + a1.w) + (a2.w + a3.w)) + ((a4.w + a5.w) + (a6.w + a7.w));
            }
            for (; j + 4 <= m; j += 4) {
                const float4 a0 = base[(size_t)slist[j + 0] * cD4];
                const float4 a1 = base[(size_t)slist[j + 1] * cD4];
                const float4 a2 = base[(size_t)slist[j + 2] * cD4];
                const float4 a3 = base[(size_t)slist[j + 3] * cD4];
                ax += (a0.x + a1.x) + (a2.x + a3.x);
                ay += (a0.y + a1.y) + (a2.y + a3.y);
                az += (a0.z + a1.z) + (a2.z + a3.z);
                aw += (a0.w + a1.w) + (a2.w + a3.w);
            }
            for (; j < m; ++j) {
                const float4 a0 = base[(size_t)slist[j] * cD4];
                ax += a0.x; ay += a0.y; az += a0.z; aw += a0.w;
            }
            wgt = 1.0f / (float)m;
        }
    }

    const int sid = step_ids[row];
    const float4 se = step_tab[(size_t)sid * cD4 + tid];
    const float4 g  = ln_g[tid];
    const float4 bb = ln_b[tid];
    float4 o;
    o.x = (x.x - mu) * rs * g.x + bb.x + se.x + ax * wgt;
    o.y = (x.y - mu) * rs * g.y + bb.y + se.y + ay * wgt;
    o.z = (x.z - mu) * rs * g.z + bb.z + se.z + az * wgt;
    o.w = (x.w - mu) * rs * g.w + bb.w + se.w + aw * wgt;
    out[(size_t)row * cD4 + tid] = o;

    // visited rows join the ticket; 5th arriver combines partials onto base
    if (tvis >= 0) {
        const int bt = b * cT + tvis;
        __threadfence();
        __syncthreads();
        if (tid == 0) sOld = atomicAdd(&ticket[bt], 1);
        __syncthreads();
        if (sOld == cNQ) {
            __threadfence();
            const int len = slen[tvis];
            const float w = 1.0f / (float)len;
            const size_t pb = (size_t)(bt * cNQ) * cD4 + tid;
            const float4 p0 = wsp[pb];
            const float4 p1 = wsp[pb + cD4];
            const float4 p2 = wsp[pb + 2 * cD4];
            const float4 p3 = wsp[pb + 3 * cD4];
            float4 oo = out[(size_t)row * cD4 + tid];
            oo.x += ((p0.x + p1.x) + (p2.x + p3.x)) * w;
            oo.y += ((p0.y + p1.y) + (p2.y + p3.y)) * w;
            oo.z += ((p0.z + p1.z) + (p2.z + p3.z)) * w;
            oo.w += ((p0.w + p1.w) + (p2.w + p3.w)) * w;
            out[(size_t)row * cD4 + tid] = oo;
        }
    }
}

// ---------------------------------------------------------------------------
extern "C" void kernel_launch(void* const* d_in, const int* in_sizes, int n_in,
                              void* d_out, int out_size, void* d_ws, size_t ws_size,
                              hipStream_t stream) {
    const float* emb      = (const float*)d_in[0];   // [B,T,V,D]
    const float* pos_fts  = (const float*)d_in[1];   // [B,N,7]
    const float* step_tab = (const float*)d_in[2];   // [100,D]
    const float* pos_w    = (const float*)d_in[3];   // [7,D]
    const float* pos_b    = (const float*)d_in[4];   // [D]
    const float* ln_g     = (const float*)d_in[5];   // [D]
    const float* ln_b     = (const float*)d_in[6];   // [D]
    const int*   vp_lens  = (const int*)d_in[7];     // [B,T]
    const int*   vpids    = (const int*)d_in[8];     // [B,T]
    const int*   cand     = (const int*)d_in[9];     // [B,T,V]
    const int*   step_ids = (const int*)d_in[10];    // [B,N]
    // d_in[11] = gmap_lens — unused by the reference output

    int*    ticket = (int*)d_ws;                     // 480 ints
    float4* wsp    = (float4*)((char*)d_ws + 2048);  // 480*4*192 float4 = 5.9 MB

    (void)hipMemsetAsync(ticket, 0, cB * cT * sizeof(int), stream);
    dim3 grid(cN + cXB, cB);
    k_all<<<grid, 192, 0, stream>>>((const float4*)emb, pos_fts,
                                    (const float4*)step_tab,
                                    (const float4*)pos_w, (const float4*)pos_b,
                                    (const float4*)ln_g, (const float4*)ln_b,
                                    vp_lens, vpids, cand, step_ids,
                                    ticket, wsp, (float4*)d_out);
}

// Round 8
// 34.747 us; speedup vs baseline: 11.5531x; 11.5531x over previous
//
#include <hip/hip_runtime.h>

// Problem dims (fixed by the reference)
constexpr int cB = 32, cT = 15, cV = 100, cD = 768, cN = 160, cAP = 7;
constexpr int cD4 = cD / 4;         // 192 float4 per row
constexpr int cTV = cT * cV;        // 1500 candidate entries per batch
constexpr int cNQ = 8;              // partial eighths per visited step
constexpr int cXB = cNQ * cT;       // 120 helper blocks per batch
constexpr float cLN_EPS = 1e-12f;

// ---------------------------------------------------------------------------
// K1: grid (cN + 120, cB) x 192.
//   nb <  cN : output-row block (pos GEMV + LN + step emb; candidate gather).
//              Visited rows write base only (no gather).
//   nb >= cN : helper block -> sum eighth q of step t into ws partial
//              (one writer per slot, no atomics, no fences).
__global__ __launch_bounds__(192) void k_main(
    const float4* __restrict__ emb,      // [B*T*V, D/4]
    const float*  __restrict__ pos_fts,  // [B,N,7]
    const float4* __restrict__ step_tab, // [100, D/4]
    const float4* __restrict__ pos_w,    // [7, D/4]
    const float4* __restrict__ pos_b,    // [D/4]
    const float4* __restrict__ ln_g,     // [D/4]
    const float4* __restrict__ ln_b,     // [D/4]
    const int*    __restrict__ vp_lens,  // [B,T]
    const int*    __restrict__ vpids,    // [B,T]
    const int*    __restrict__ cand_ids, // [B,T,V]
    const int*    __restrict__ step_ids, // [B,N]
    float4*       __restrict__ wsp,      // [B*T*8, D/4] partial sums
    float4*       __restrict__ out)      // [B*N, D/4]
{
    const int nb  = blockIdx.x;          // 0..cN+119
    const int b   = blockIdx.y;          // 0..31
    const int tid = threadIdx.x;         // 0..191, owns float4 slot tid

    __shared__ int   slen[cT], svp[cT];
    __shared__ float sf[cAP];
    __shared__ float red[8];
    __shared__ int   scount;
    __shared__ int   slist[cTV];         // contributor entries (t*V+v), 6 KB

    if (tid < cT) slen[tid] = vp_lens[b * cT + tid];
    if (tid >= 32 && tid < 32 + cT) svp[tid - 32] = vpids[b * cT + (tid - 32)];

    // ---------------- helper blocks: one eighth of one step ----------------
    if (nb >= cN) {
        __syncthreads();
        const int j  = nb - cN;          // 0..119
        const int t  = j >> 3;
        const int q  = j & 7;
        const int bt = b * cT + t;
        const int len = slen[t];
        const int lo = (len * q) >> 3;
        const int hi = (len * (q + 1)) >> 3;
        float ax0 = 0.f, ay0 = 0.f, az0 = 0.f, aw0 = 0.f;
        float ax1 = 0.f, ay1 = 0.f, az1 = 0.f, aw1 = 0.f;
        const float4* base = emb + (size_t)bt * cV * cD4 + tid;
        int i = lo;
        for (; i + 8 <= hi; i += 8) {
            const float4 a0 = base[(size_t)(i + 0) * cD4];
            const float4 a1 = base[(size_t)(i + 1) * cD4];
            const float4 a2 = base[(size_t)(i + 2) * cD4];
            const float4 a3 = base[(size_t)(i + 3) * cD4];
            const float4 a4 = base[(size_t)(i + 4) * cD4];
            const float4 a5 = base[(size_t)(i + 5) * cD4];
            const float4 a6 = base[(size_t)(i + 6) * cD4];
            const float4 a7 = base[(size_t)(i + 7) * cD4];
            ax0 += (a0.x + a1.x) + (a2.x + a3.x);
            ay0 += (a0.y + a1.y) + (a2.y + a3.y);
            az0 += (a0.z + a1.z) + (a2.z + a3.z);
            aw0 += (a0.w + a1.w) + (a2.w + a3.w);
            ax1 += (a4.x + a5.x) + (a6.x + a7.x);
            ay1 += (a4.y + a5.y) + (a6.y + a7.y);
            az1 += (a4.z + a5.z) + (a6.z + a7.z);
            aw1 += (a4.w + a5.w) + (a6.w + a7.w);
        }
        for (; i + 4 <= hi; i += 4) {
            const float4 a0 = base[(size_t)(i + 0) * cD4];
            const float4 a1 = base[(size_t)(i + 1) * cD4];
            const float4 a2 = base[(size_t)(i + 2) * cD4];
            const float4 a3 = base[(size_t)(i + 3) * cD4];
            ax0 += (a0.x + a1.x) + (a2.x + a3.x);
            ay0 += (a0.y + a1.y) + (a2.y + a3.y);
            az0 += (a0.z + a1.z) + (a2.z + a3.z);
            aw0 += (a0.w + a1.w) + (a2.w + a3.w);
        }
        for (; i < hi; ++i) {
            const float4 a0 = base[(size_t)i * cD4];
            ax0 += a0.x; ay0 += a0.y; az0 += a0.z; aw0 += a0.w;
        }
        wsp[(size_t)(bt * cNQ + q) * cD4 + tid] =
            make_float4(ax0 + ax1, ay0 + ay1, az0 + az1, aw0 + aw1);
        return;
    }

    // ---------------- output-row blocks ----------------
    const int n   = nb;
    const int row = b * cN + n;
    if (tid >= 64 && tid < 64 + cAP) sf[tid - 64] = pos_fts[row * cAP + (tid - 64)];
    if (tid == 0) scount = 0;
    __syncthreads();

    // which step visited this node (largest t wins, matches scatter override)
    int tvis = -1;
#pragma unroll
    for (int k = cT - 1; k >= 0; --k) if (tvis < 0 && svp[k] == n) tvis = k;

    // candidate rows: scan this batch's 1500 cand ids (int4) + LDS compact
    const bool isCand = (n > 0) && (tvis < 0);
    if (isCand) {
        const int4* cb4 = (const int4*)(cand_ids + (size_t)b * cTV);
        for (int u = tid; u < cTV / 4; u += 192) {
            const int4 c4 = cb4[u];
            const int e0 = u * 4;
            const int cc[4] = {c4.x, c4.y, c4.z, c4.w};
#pragma unroll
            for (int k = 0; k < 4; ++k) {
                const int e = e0 + k;
                const int t = e / cV;
                const int v = e - t * cV;
                if (cc[k] == n && v < slen[t]) slist[atomicAdd(&scount, 1)] = e;
            }
        }
    }

    // pos GEMV: 4 outputs per thread (overlaps the scan's loads)
    float4 x = pos_b[tid];
#pragma unroll
    for (int k = 0; k < cAP; ++k) {
        const float4 w = pos_w[k * cD4 + tid];
        const float f = sf[k];
        x.x = fmaf(f, w.x, x.x); x.y = fmaf(f, w.y, x.y);
        x.z = fmaf(f, w.z, x.z); x.w = fmaf(f, w.w, x.w);
    }
    float s  = x.x + x.y + x.z + x.w;
    float ss = x.x * x.x + x.y * x.y + x.z * x.z + x.w * x.w;
    for (int off = 32; off; off >>= 1) {
        s  += __shfl_down(s,  off, 64);
        ss += __shfl_down(ss, off, 64);
    }
    if ((tid & 63) == 0) { red[(tid >> 6) * 2] = s; red[(tid >> 6) * 2 + 1] = ss; }
    __syncthreads();                      // also orders slist writes
    if (tid == 0) {
        const float S  = red[0] + red[2] + red[4];
        const float SS = red[1] + red[3] + red[5];
        const float mu  = S / (float)cD;
        const float var = SS / (float)cD - mu * mu;
        red[6] = mu;
        red[7] = rsqrtf(fmaxf(var, 0.f) + cLN_EPS);
    }
    __syncthreads();
    const float mu = red[6], rs = red[7];

    // candidate gather (visited rows: helpers + K2 supply everything)
    float ax0 = 0.f, ay0 = 0.f, az0 = 0.f, aw0 = 0.f;
    float ax1 = 0.f, ay1 = 0.f, az1 = 0.f, aw1 = 0.f;
    float wgt = 0.f;
    if (isCand) {
        const int m = scount;
        if (m > 0) {
            const float4* base = emb + (size_t)b * cTV * cD4 + tid;
            int j = 0;
            for (; j + 8 <= m; j += 8) {
                const float4 a0 = base[(size_t)slist[j + 0] * cD4];
                const float4 a1 = base[(size_t)slist[j + 1] * cD4];
                const float4 a2 = base[(size_t)slist[j + 2] * cD4];
                const float4 a3 = base[(size_t)slist[j + 3] * cD4];
                const float4 a4 = base[(size_t)slist[j + 4] * cD4];
                const float4 a5 = base[(size_t)slist[j + 5] * cD4];
                const float4 a6 = base[(size_t)slist[j + 6] * cD4];
                const float4 a7 = base[(size_t)slist[j + 7] * cD4];
                ax0 += (a0.x + a1.x) + (a2.x + a3.x);
                ay0 += (a0.y + a1.y) + (a2.y + a3.y);
                az0 += (a0.z + a1.z) + (a2.z + a3.z);
                aw0 += (a0.w + a1.w) + (a2.w + a3.w);
                ax1 += (a4.x + a5.x) + (a6.x + a7.x);
                ay1 += (a4.y + a5.y) + (a6.y + a7.y);
                az1 += (a4.z + a5.z) + (a6.z + a7.z);
                aw1 += (a4.w + a5.w) + (a6.w + a7.w);
            }
            for (; j + 4 <= m; j += 4) {
                const float4 a0 = base[(size_t)slist[j + 0] * cD4];
                const float4 a1 = base[(size_t)slist[j + 1] * cD4];
                const float4 a2 = base[(size_t)slist[j + 2] * cD4];
                const float4 a3 = base[(size_t)slist[j + 3] * cD4];
                ax0 += (a0.x + a1.x) + (a2.x + a3.x);
                ay0 += (a0.y + a1.y) + (a2.y + a3.y);
                az0 += (a0.z + a1.z) + (a2.z + a3.z);
                aw0 += (a0.w + a1.w) + (a2.w + a3.w);
            }
            for (; j < m; ++j) {
                const float4 a0 = base[(size_t)slist[j] * cD4];
                ax0 += a0.x; ay0 += a0.y; az0 += a0.z; aw0 += a0.w;
            }
            wgt = 1.0f / (float)m;
        }
    }

    const int sid = step_ids[row];
    const float4 se = step_tab[(size_t)sid * cD4 + tid];
    const float4 g  = ln_g[tid];
    const float4 bb = ln_b[tid];
    float4 o;
    o.x = (x.x - mu) * rs * g.x + bb.x + se.x + (ax0 + ax1) * wgt;
    o.y = (x.y - mu) * rs * g.y + bb.y + se.y + (ay0 + ay1) * wgt;
    o.z = (x.z - mu) * rs * g.z + bb.z + se.z + (az0 + az1) * wgt;
    o.w = (x.w - mu) * rs * g.w + bb.w + se.w + (aw0 + aw1) * wgt;
    out[(size_t)row * cD4 + tid] = o;
}

// ---------------------------------------------------------------------------
// K2: add the eight helper partials * (1/len) into each visited row.
__global__ __launch_bounds__(192) void k_fix(
    const int*    __restrict__ vp_lens,  // [B,T]
    const int*    __restrict__ vpids,    // [B,T]
    const float4* __restrict__ wsp,      // [B*T*8, D/4]
    float4*       __restrict__ out)      // [B*N, D/4]
{
    const int t = blockIdx.x;            // 0..14
    const int b = blockIdx.y;            // 0..31
    const int node = vpids[b * cT + t];
    if (node <= 0 || node >= cN) return;
    const int len = vp_lens[b * cT + t];
    const int tid = threadIdx.x;
    const size_t pb = (size_t)((b * cT + t) * cNQ) * cD4 + tid;
    float sx = 0.f, sy = 0.f, sz = 0.f, sw = 0.f;
#pragma unroll
    for (int q = 0; q < cNQ; ++q) {
        const float4 p = wsp[pb + (size_t)q * cD4];
        sx += p.x; sy += p.y; sz += p.z; sw += p.w;
    }
    const float w = 1.0f / (float)len;
    const size_t orow = (size_t)(b * cN + node) * cD4 + tid;
    float4 o = out[orow];
    o.x += sx * w; o.y += sy * w; o.z += sz * w; o.w += sw * w;
    out[orow] = o;
}

// ---------------------------------------------------------------------------
extern "C" void kernel_launch(void* const* d_in, const int* in_sizes, int n_in,
                              void* d_out, int out_size, void* d_ws, size_t ws_size,
                              hipStream_t stream) {
    const float* emb      = (const float*)d_in[0];   // [B,T,V,D]
    const float* pos_fts  = (const float*)d_in[1];   // [B,N,7]
    const float* step_tab = (const float*)d_in[2];   // [100,D]
    const float* pos_w    = (const float*)d_in[3];   // [7,D]
    const float* pos_b    = (const float*)d_in[4];   // [D]
    const float* ln_g     = (const float*)d_in[5];   // [D]
    const float* ln_b     = (const float*)d_in[6];   // [D]
    const int*   vp_lens  = (const int*)d_in[7];     // [B,T]
    const int*   vpids    = (const int*)d_in[8];     // [B,T]
    const int*   cand     = (const int*)d_in[9];     // [B,T,V]
    const int*   step_ids = (const int*)d_in[10];    // [B,N]
    // d_in[11] = gmap_lens — unused by the reference output

    float4* wsp = (float4*)d_ws;        // 480*8*192 float4 = 11.8 MB

    dim3 g1(cN + cXB, cB);
    k_main<<<g1, 192, 0, stream>>>((const float4*)emb, pos_fts,
                                   (const float4*)step_tab,
                                   (const float4*)pos_w, (const float4*)pos_b,
                                   (const float4*)ln_g, (const float4*)ln_b,
                                   vp_lens, vpids, cand, step_ids,
                                   wsp, (float4*)d_out);
    dim3 g2(cT, cB);
    k_fix<<<g2, 192, 0, stream>>>(vp_lens, vpids, wsp, (float4*)d_out);
}

// Round 9
// 32.438 us; speedup vs baseline: 12.3754x; 1.0712x over previous
//
#include <hip/hip_runtime.h>

// Problem dims (fixed by the reference)
constexpr int cB = 32, cT = 15, cV = 100, cD = 768, cN = 160, cAP = 7;
constexpr int cD4 = cD / 4;         // 192 float4 per row
constexpr int cTV = cT * cV;        // 1500 candidate entries per batch
constexpr int cXB = 3 * cT;         // 45 helper blocks per batch (quarters 1..3)
constexpr float cLN_EPS = 1e-12f;

// dual-chain unroll-8 row accumulator (rows [lo,hi) of `base`, stride cD4)
__device__ __forceinline__ void sum_rows(const float4* __restrict__ base,
                                         int lo, int hi,
                                         float& ax, float& ay, float& az, float& aw) {
    float ax1 = 0.f, ay1 = 0.f, az1 = 0.f, aw1 = 0.f;
    int i = lo;
    for (; i + 8 <= hi; i += 8) {
        const float4 a0 = base[(size_t)(i + 0) * cD4];
        const float4 a1 = base[(size_t)(i + 1) * cD4];
        const float4 a2 = base[(size_t)(i + 2) * cD4];
        const float4 a3 = base[(size_t)(i + 3) * cD4];
        const float4 a4 = base[(size_t)(i + 4) * cD4];
        const float4 a5 = base[(size_t)(i + 5) * cD4];
        const float4 a6 = base[(size_t)(i + 6) * cD4];
        const float4 a7 = base[(size_t)(i + 7) * cD4];
        ax  += (a0.x + a1.x) + (a2.x + a3.x);
        ay  += (a0.y + a1.y) + (a2.y + a3.y);
        az  += (a0.z + a1.z) + (a2.z + a3.z);
        aw  += (a0.w + a1.w) + (a2.w + a3.w);
        ax1 += (a4.x + a5.x) + (a6.x + a7.x);
        ay1 += (a4.y + a5.y) + (a6.y + a7.y);
        az1 += (a4.z + a5.z) + (a6.z + a7.z);
        aw1 += (a4.w + a5.w) + (a6.w + a7.w);
    }
    for (; i + 4 <= hi; i += 4) {
        const float4 a0 = base[(size_t)(i + 0) * cD4];
        const float4 a1 = base[(size_t)(i + 1) * cD4];
        const float4 a2 = base[(size_t)(i + 2) * cD4];
        const float4 a3 = base[(size_t)(i + 3) * cD4];
        ax += (a0.x + a1.x) + (a2.x + a3.x);
        ay += (a0.y + a1.y) + (a2.y + a3.y);
        az += (a0.z + a1.z) + (a2.z + a3.z);
        aw += (a0.w + a1.w) + (a2.w + a3.w);
    }
    for (; i < hi; ++i) {
        const float4 a0 = base[(size_t)i * cD4];
        ax += a0.x; ay += a0.y; az += a0.z; aw += a0.w;
    }
    ax += ax1; ay += ay1; az += az1; aw += aw1;
}

// ---------------------------------------------------------------------------
// K1: grid (cN + 45, cB) x 192.  (round-6 structure, unroll-8 loops)
__global__ __launch_bounds__(192) void k_main(
    const float4* __restrict__ emb,      // [B*T*V, D/4]
    const float*  __restrict__ pos_fts,  // [B,N,7]
    const float4* __restrict__ step_tab, // [100, D/4]
    const float4* __restrict__ pos_w,    // [7, D/4]
    const float4* __restrict__ pos_b,    // [D/4]
    const float4* __restrict__ ln_g,     // [D/4]
    const float4* __restrict__ ln_b,     // [D/4]
    const int*    __restrict__ vp_lens,  // [B,T]
    const int*    __restrict__ vpids,    // [B,T]
    const int*    __restrict__ cand_ids, // [B,T,V]
    const int*    __restrict__ step_ids, // [B,N]
    float4*       __restrict__ wsp,      // [B*T*3, D/4] partial sums
    float4*       __restrict__ out)      // [B*N, D/4]
{
    const int nb  = blockIdx.x;          // 0..cN+44
    const int b   = blockIdx.y;          // 0..31
    const int tid = threadIdx.x;         // 0..191, owns float4 slot tid

    __shared__ int   slen[cT], svp[cT];
    __shared__ float sf[cAP];
    __shared__ float red[8];
    __shared__ int   scount;
    __shared__ int   slist[cTV];         // contributor entries (t*V+v), 6 KB

    if (tid < cT) slen[tid] = vp_lens[b * cT + tid];
    if (tid >= 32 && tid < 32 + cT) svp[tid - 32] = vpids[b * cT + (tid - 32)];

    // ---------------- helper blocks: one quarter (1..3) of one step --------
    if (nb >= cN) {
        __syncthreads();
        const int j = nb - cN;           // 0..44
        const int t = j / 3;
        const int q = j - t * 3 + 1;     // quarter 1..3
        const int bt = b * cT + t;
        const int len = slen[t];
        const int lo = (len * q) >> 2;
        const int hi = (len * (q + 1)) >> 2;
        float ax = 0.f, ay = 0.f, az = 0.f, aw = 0.f;
        sum_rows(emb + (size_t)bt * cV * cD4 + tid, lo, hi, ax, ay, az, aw);
        wsp[(size_t)(bt * 3 + (q - 1)) * cD4 + tid] = make_float4(ax, ay, az, aw);
        return;
    }

    // ---------------- output-row blocks ----------------
    const int n   = nb;
    const int row = b * cN + n;
    if (tid >= 64 && tid < 64 + cAP) sf[tid - 64] = pos_fts[row * cAP + (tid - 64)];
    if (tid == 0) scount = 0;
    __syncthreads();

    // which step visited this node
    int tvis = -1;
#pragma unroll
    for (int k = cT - 1; k >= 0; --k) if (tvis < 0 && svp[k] == n) tvis = k;

    // candidate rows: scan this batch's 1500 cand ids (int4) + LDS compact
    const bool isCand = (n > 0) && (tvis < 0);
    if (isCand) {
        const int4* cb4 = (const int4*)(cand_ids + (size_t)b * cTV);
        for (int u = tid; u < cTV / 4; u += 192) {
            const int4 c4 = cb4[u];
            const int e0 = u * 4;
            const int cc[4] = {c4.x, c4.y, c4.z, c4.w};
#pragma unroll
            for (int k = 0; k < 4; ++k) {
                const int e = e0 + k;
                const int t = e / cV;
                const int v = e - t * cV;
                if (cc[k] == n && v < slen[t]) slist[atomicAdd(&scount, 1)] = e;
            }
        }
    }

    // pos GEMV: 4 outputs per thread (overlaps the scan's loads)
    float4 x = pos_b[tid];
#pragma unroll
    for (int k = 0; k < cAP; ++k) {
        const float4 w = pos_w[k * cD4 + tid];
        const float f = sf[k];
        x.x = fmaf(f, w.x, x.x); x.y = fmaf(f, w.y, x.y);
        x.z = fmaf(f, w.z, x.z); x.w = fmaf(f, w.w, x.w);
    }
    float s  = x.x + x.y + x.z + x.w;
    float ss = x.x * x.x + x.y * x.y + x.z * x.z + x.w * x.w;
    for (int off = 32; off; off >>= 1) {
        s  += __shfl_down(s,  off, 64);
        ss += __shfl_down(ss, off, 64);
    }
    if ((tid & 63) == 0) { red[(tid >> 6) * 2] = s; red[(tid >> 6) * 2 + 1] = ss; }
    __syncthreads();                      // also orders slist writes
    if (tid == 0) {
        const float S  = red[0] + red[2] + red[4];
        const float SS = red[1] + red[3] + red[5];
        const float mu  = S / (float)cD;
        const float var = SS / (float)cD - mu * mu;
        red[6] = mu;
        red[7] = rsqrtf(fmaxf(var, 0.f) + cLN_EPS);
    }
    __syncthreads();
    const float mu = red[6], rs = red[7];

    // gather image feature
    float ax = 0.f, ay = 0.f, az = 0.f, aw = 0.f;
    float wgt = 0.f;
    if (n > 0) {
        if (tvis >= 0) {
            // visited node: quarter 0 only (helpers + K2 supply quarters 1..3)
            const int len = slen[tvis];
            sum_rows(emb + (size_t)(b * cT + tvis) * cV * cD4 + tid,
                     0, len >> 2, ax, ay, az, aw);
            wgt = 1.0f / (float)len;
        } else {
            const int m = scount;
            if (m > 0) {
                const float4* base = emb + (size_t)b * cTV * cD4 + tid;
                float ax1 = 0.f, ay1 = 0.f, az1 = 0.f, aw1 = 0.f;
                int j = 0;
                for (; j + 8 <= m; j += 8) {
                    const float4 a0 = base[(size_t)slist[j + 0] * cD4];
                    const float4 a1 = base[(size_t)slist[j + 1] * cD4];
                    const float4 a2 = base[(size_t)slist[j + 2] * cD4];
                    const float4 a3 = base[(size_t)slist[j + 3] * cD4];
                    const float4 a4 = base[(size_t)slist[j + 4] * cD4];
                    const float4 a5 = base[(size_t)slist[j + 5] * cD4];
                    const float4 a6 = base[(size_t)slist[j + 6] * cD4];
                    const float4 a7 = base[(size_t)slist[j + 7] * cD4];
                    ax  += (a0.x + a1.x) + (a2.x + a3.x);
                    ay  += (a0.y + a1.y) + (a2.y + a3.y);
                    az  += (a0.z + a1.z) + (a2.z + a3.z);
                    aw  += (a0.w + a1.w) + (a2.w + a3.w);
                    ax1 += (a4.x + a5.x) + (a6.x + a7.x);
                    ay1 += (a4.y + a5.y) + (a6.y + a7.y);
                    az1 += (a4.z + a5.z) + (a6.z + a7.z);
                    aw1 += (a4.w + a5.w) + (a6.w + a7.w);
                }
                for (; j + 4 <= m; j += 4) {
                    const float4 a0 = base[(size_t)slist[j + 0] * cD4];
                    const float4 a1 = base[(size_t)slist[j + 1] * cD4];
                    const float4 a2 = base[(size_t)slist[j + 2] * cD4];
                    const float4 a3 = base[(size_t)slist[j + 3] * cD4];
                    ax += (a0.x + a1.x) + (a2.x + a3.x);
                    ay += (a0.y + a1.y) + (a2.y + a3.y);
                    az += (a0.z + a1.z) + (a2.z + a3.z);
                    aw += (a0.w + a1.w) + (a2.w + a3.w);
                }
                for (; j < m; ++j) {
                    const float4 a0 = base[(size_t)slist[j] * cD4];
                    ax += a0.x; ay += a0.y; az += a0.z; aw += a0.w;
                }
                ax += ax1; ay += ay1; az += az1; aw += aw1;
                wgt = 1.0f / (float)m;
            }
        }
    }

    const int sid = step_ids[row];
    const float4 se = step_tab[(size_t)sid * cD4 + tid];
    const float4 g  = ln_g[tid];
    const float4 bb = ln_b[tid];
    float4 o;
    o.x = (x.x - mu) * rs * g.x + bb.x + se.x + ax * wgt;
    o.y = (x.y - mu) * rs * g.y + bb.y + se.y + ay * wgt;
    o.z = (x.z - mu) * rs * g.z + bb.z + se.z + az * wgt;
    o.w = (x.w - mu) * rs * g.w + bb.w + se.w + aw * wgt;
    out[(size_t)row * cD4 + tid] = o;
}

// ---------------------------------------------------------------------------
// K2: add the three helper partials * (1/len) into each visited row.
__global__ __launch_bounds__(192) void k_fix(
    const int*    __restrict__ vp_lens,  // [B,T]
    const int*    __restrict__ vpids,    // [B,T]
    const float4* __restrict__ wsp,      // [B*T*3, D/4]
    float4*       __restrict__ out)      // [B*N, D/4]
{
    const int t = blockIdx.x;            // 0..14
    const int b = blockIdx.y;            // 0..31
    const int node = vpids[b * cT + t];
    if (node <= 0 || node >= cN) return;
    const int len = vp_lens[b * cT + t];
    const int tid = threadIdx.x;
    const size_t pb = (size_t)((b * cT + t) * 3) * cD4 + tid;
    const float4 p0 = wsp[pb];
    const float4 p1 = wsp[pb + cD4];
    const float4 p2 = wsp[pb + 2 * cD4];
    const float w = 1.0f / (float)len;
    const size_t orow = (size_t)(b * cN + node) * cD4 + tid;
    float4 o = out[orow];
    o.x += ((p0.x + p1.x) + p2.x) * w;
    o.y += ((p0.y + p1.y) + p2.y) * w;
    o.z += ((p0.z + p1.z) + p2.z) * w;
    o.w += ((p0.w + p1.w) + p2.w) * w;
    out[orow] = o;
}

// ---------------------------------------------------------------------------
extern "C" void kernel_launch(void* const* d_in, const int* in_sizes, int n_in,
                              void* d_out, int out_size, void* d_ws, size_t ws_size,
                              hipStream_t stream) {
    const float* emb      = (const float*)d_in[0];   // [B,T,V,D]
    const float* pos_fts  = (const float*)d_in[1];   // [B,N,7]
    const float* step_tab = (const float*)d_in[2];   // [100,D]
    const float* pos_w    = (const float*)d_in[3];   // [7,D]
    const float* pos_b    = (const float*)d_in[4];   // [D]
    const float* ln_g     = (const float*)d_in[5];   // [D]
    const float* ln_b     = (const float*)d_in[6];   // [D]
    const int*   vp_lens  = (const int*)d_in[7];     // [B,T]
    const int*   vpids    = (const int*)d_in[8];     // [B,T]
    const int*   cand     = (const int*)d_in[9];     // [B,T,V]
    const int*   step_ids = (const int*)d_in[10];    // [B,N]
    // d_in[11] = gmap_lens — unused by the reference output

    float4* wsp = (float4*)d_ws;        // 480*3*192 float4 = 4.4 MB

    dim3 g1(cN + cXB, cB);
    k_main<<<g1, 192, 0, stream>>>((const float4*)emb, pos_fts,
                                   (const float4*)step_tab,
                                   (const float4*)pos_w, (const float4*)pos_b,
                                   (const float4*)ln_g, (const float4*)ln_b,
                                   vp_lens, vpids, cand, step_ids,
                                   wsp, (float4*)d_out);
    dim3 g2(cT, cB);
    k_fix<<<g2, 192, 0, stream>>>(vp_lens, vpids, wsp, (float4*)d_out);
}